// Round 1
// baseline (12835.269 us; speedup 1.0000x reference)
//
#include <hip/hip_runtime.h>

// ---------------- problem constants ----------------
namespace {
constexpr int kN = 32768, kIN = 768, kH1 = 2048, kH2 = 1024, kE = 64, kNE = 256;
constexpr int kKP = 4096, kTT = 8192;
constexpr int kChunk = 4096;  // rows per GEMM slice (bounds ws use)

// flat float32 offsets in d_out, reference return order
constexpr size_t OFF_OUT = 0;
constexpr size_t OFF_VQ  = (size_t)kN * kIN;          // 25165824
constexpr size_t OFF_IDX = OFF_VQ + 1;                // idx as float values
constexpr size_t OFF_XQ  = OFF_IDX + (size_t)kN;      // x_q_st = codebook[idx]
constexpr size_t OFF_OCL = OFF_XQ + (size_t)kN * kE;
constexpr size_t OFF_ITL = OFF_OCL + 1;
constexpr size_t OFF_QDA = OFF_ITL + 1;
}  // namespace

// ---------------- fp32 tiled GEMM: C = relu?(A@B + bias) ----------------
// A: MxK row-major, B: KxN row-major, C: MxN row-major. All dims divide tiles.
template <int BM, int BN, int BK, int TM, int TN, bool RELU>
__global__ __launch_bounds__(256) void sgemm(const float* __restrict__ A,
                                             const float* __restrict__ B,
                                             const float* __restrict__ bias,
                                             float* __restrict__ C,
                                             int M, int N, int K) {
  __shared__ float As[BK][BM];  // stored transposed: As[k][m]
  __shared__ float Bs[BK][BN];
  const int tid = threadIdx.x;
  const int col0 = blockIdx.x * BN;
  const int row0 = blockIdx.y * BM;
  const int tx = tid % (BN / TN);
  const int ty = tid / (BN / TN);
  float acc[TM][TN];
#pragma unroll
  for (int m = 0; m < TM; ++m)
#pragma unroll
    for (int n = 0; n < TN; ++n) acc[m][n] = 0.f;

  constexpr int ALOADS = (BM * BK) / (4 * 256);
  constexpr int BLOADS = (BK * BN) / (4 * 256);

  for (int k0 = 0; k0 < K; k0 += BK) {
#pragma unroll
    for (int i = 0; i < ALOADS; ++i) {
      int q = tid + 256 * i;
      int r = q / (BK / 4);
      int c4 = (q % (BK / 4)) * 4;
      float4 v = *(const float4*)(A + (size_t)(row0 + r) * K + k0 + c4);
      As[c4 + 0][r] = v.x;
      As[c4 + 1][r] = v.y;
      As[c4 + 2][r] = v.z;
      As[c4 + 3][r] = v.w;
    }
#pragma unroll
    for (int i = 0; i < BLOADS; ++i) {
      int q = tid + 256 * i;
      int r = q / (BN / 4);
      int c4 = (q % (BN / 4)) * 4;
      *(float4*)(&Bs[r][c4]) = *(const float4*)(B + (size_t)(k0 + r) * N + col0 + c4);
    }
    __syncthreads();
#pragma unroll
    for (int k = 0; k < BK; ++k) {
      float a[TM], b[TN];
#pragma unroll
      for (int m = 0; m < TM; m += 4)
        *(float4*)(&a[m]) = *(const float4*)(&As[k][ty * TM + m]);
#pragma unroll
      for (int n = 0; n < TN; n += 4)
        *(float4*)(&b[n]) = *(const float4*)(&Bs[k][tx * TN + n]);
#pragma unroll
      for (int m = 0; m < TM; ++m)
#pragma unroll
        for (int n = 0; n < TN; ++n) acc[m][n] = fmaf(a[m], b[n], acc[m][n]);
    }
    __syncthreads();
  }
#pragma unroll
  for (int m = 0; m < TM; ++m) {
    size_t r = (size_t)row0 + ty * TM + m;
#pragma unroll
    for (int n = 0; n < TN; ++n) {
      int c = col0 + tx * TN + n;
      float v = acc[m][n] + bias[c];
      if (RELU) v = fmaxf(v, 0.f);
      C[r * N + c] = v;
    }
  }
}

// ---------------- VQ: argmin over 256 codes, write idx/x_q_st/xn, vq partial ----------------
__global__ __launch_bounds__(256) void vq_kernel(const float* __restrict__ z,
                                                 const float* __restrict__ cb,
                                                 float* __restrict__ idx_out,
                                                 float* __restrict__ xq_out,
                                                 float* __restrict__ xn_out,
                                                 float* __restrict__ acc) {
  __shared__ float zs[kE];
  __shared__ float rv[256];
  __shared__ int ri[256];
  const int i = blockIdx.x;
  const int t = threadIdx.x;
  if (t < kE) zs[t] = z[(size_t)i * kE + t];
  __syncthreads();
  // thread t evaluates codebook entry t: ||cb||^2 - 2 z.cb (||z||^2 const per row)
  float dot = 0.f, nrm = 0.f;
  const float* c = cb + (size_t)t * kE;
#pragma unroll 8
  for (int e = 0; e < kE; ++e) {
    float ce = c[e];
    dot = fmaf(zs[e], ce, dot);
    nrm = fmaf(ce, ce, nrm);
  }
  rv[t] = nrm - 2.f * dot;
  ri[t] = t;
  __syncthreads();
  for (int s = 128; s > 0; s >>= 1) {
    if (t < s) {
      float v2 = rv[t + s];
      int i2 = ri[t + s];
      if (v2 < rv[t] || (v2 == rv[t] && i2 < ri[t])) { rv[t] = v2; ri[t] = i2; }
    }
    __syncthreads();
  }
  const int best = ri[0];
  if (t == 0) idx_out[i] = (float)best;
  if (t < kE) {  // wave 0 only
    float xq = cb[(size_t)best * kE + t];
    xq_out[(size_t)i * kE + t] = xq;
    float d = xq - zs[t];
    float sq = d * d;
    float nq = xq * xq;
#pragma unroll
    for (int m = 32; m > 0; m >>= 1) {
      sq += __shfl_xor(sq, m);
      nq += __shfl_xor(nq, m);
    }
    float inv = 1.f / fmaxf(sqrtf(nq), 1e-12f);
    xn_out[(size_t)i * kE + t] = xq * inv;
    if (t == 0) atomicAdd(&acc[i & 255], sq);
  }
}

// ---------------- qd_align: sum of w_i * cos(z_i, qz_i) ----------------
__global__ __launch_bounds__(256) void qd_kernel(const float* __restrict__ z,
                                                 const float* __restrict__ qz,
                                                 const float* __restrict__ w,
                                                 float* __restrict__ acc) {
  const int i = blockIdx.x * 4 + (threadIdx.x >> 6);
  const int l = threadIdx.x & 63;
  float a = z[(size_t)i * kE + l];
  float b = qz[(size_t)i * kE + l];
  float dot = a * b, na = a * a, nb = b * b;
#pragma unroll
  for (int m = 32; m > 0; m >>= 1) {
    dot += __shfl_xor(dot, m);
    na += __shfl_xor(na, m);
    nb += __shfl_xor(nb, m);
  }
  if (l == 0) {
    float cosv = dot / fmaxf(sqrtf(na) * sqrtf(nb), 1e-8f);
    atomicAdd(&acc[i & 255], w[i] * cosv);
  }
}

// ---------------- triplet: sum relu(dp - dn + margin) ----------------
__global__ __launch_bounds__(256) void trip_kernel(const float* __restrict__ z,
                                                   const int* __restrict__ tr,
                                                   float* __restrict__ acc) {
  const int t = blockIdx.x * 4 + (threadIdx.x >> 6);
  const int l = threadIdx.x & 63;
  int ia = tr[3 * t], ip = tr[3 * t + 1], in2 = tr[3 * t + 2];
  float a = z[(size_t)ia * kE + l];
  float p = z[(size_t)ip * kE + l];
  float n = z[(size_t)in2 * kE + l];
  float d1 = (a - p) * (a - p);
  float d2 = (a - n) * (a - n);
#pragma unroll
  for (int m = 32; m > 0; m >>= 1) {
    d1 += __shfl_xor(d1, m);
    d2 += __shfl_xor(d2, m);
  }
  if (l == 0) {
    float dp = sqrtf(d1 + 1e-12f);
    float dn = sqrtf(d2 + 1e-12f);
    atomicAdd(&acc[t & 255], fmaxf(dp - dn + 0.2f, 0.f));
  }
}

// ---------------- pairs: subtract positive sim ----------------
__global__ __launch_bounds__(256) void pos_kernel(const float* __restrict__ xn,
                                                  const int* __restrict__ pairs,
                                                  float* __restrict__ acc) {
  const int k = blockIdx.x * 4 + (threadIdx.x >> 6);
  const int l = threadIdx.x & 63;
  int i0 = pairs[2 * k], i1 = pairs[2 * k + 1];
  float v = xn[(size_t)i0 * kE + l] * xn[(size_t)i1 * kE + l];
#pragma unroll
  for (int m = 32; m > 0; m >>= 1) v += __shfl_xor(v, m);
  if (l == 0) atomicAdd(&acc[k & 255], -10.f * v);  // -pos (sim = dot/0.1)
}

// ---------------- pairs: logsumexp over all N columns ----------------
// 16 pairs per block, 128-column tiles of xn staged transposed in LDS.
__global__ __launch_bounds__(256) void lse_kernel(const float* __restrict__ xn,
                                                  const int* __restrict__ pairs,
                                                  float* __restrict__ acc) {
  constexpr int PPB = 16, TJ = 128, PAD = 4;
  __shared__ float anch[PPB][kE];
  __shared__ float tileT[kE][TJ + PAD];  // [e][c]
  const int t = threadIdx.x;
  const int pb = blockIdx.x * PPB;
  for (int q = t; q < PPB * kE; q += 256) {
    int p = q >> 6, e = q & 63;
    anch[p][e] = xn[(size_t)pairs[2 * (pb + p)] * kE + e];
  }
  const int cg = t & 31;         // 32 column groups x 4 cols
  const int pg = t >> 5;         // 8 pair groups x 2 pairs
  const int c0 = cg * 4;
  const int p0 = 2 * pg, p1 = 2 * pg + 1;
  const int cload = t & 127;     // staging: this thread owns column cload
  const int eb = t >> 7;         // 0/1
  float s0 = 0.f, s1 = 0.f;
  for (int j0 = 0; j0 < kN; j0 += TJ) {
    __syncthreads();  // also covers anchor load on first iter
#pragma unroll
    for (int i = 0; i < 8; ++i) {
      int e4 = (eb + 2 * i) * 4;
      float4 v = *(const float4*)(xn + (size_t)(j0 + cload) * kE + e4);
      tileT[e4 + 0][cload] = v.x;
      tileT[e4 + 1][cload] = v.y;
      tileT[e4 + 2][cload] = v.z;
      tileT[e4 + 3][cload] = v.w;
    }
    __syncthreads();
    float4 d0 = {0.f, 0.f, 0.f, 0.f}, d1 = {0.f, 0.f, 0.f, 0.f};
#pragma unroll
    for (int e = 0; e < kE; e += 4) {
      float4 a0 = *(const float4*)(&anch[p0][e]);
      float4 a1 = *(const float4*)(&anch[p1][e]);
      float4 t0 = *(const float4*)(&tileT[e + 0][c0]);
      float4 t1 = *(const float4*)(&tileT[e + 1][c0]);
      float4 t2 = *(const float4*)(&tileT[e + 2][c0]);
      float4 t3 = *(const float4*)(&tileT[e + 3][c0]);
#define ACC4(dd, aa, tt)              \
  dd.x = fmaf(aa, tt.x, dd.x);        \
  dd.y = fmaf(aa, tt.y, dd.y);        \
  dd.z = fmaf(aa, tt.z, dd.z);        \
  dd.w = fmaf(aa, tt.w, dd.w)
      ACC4(d0, a0.x, t0); ACC4(d0, a0.y, t1); ACC4(d0, a0.z, t2); ACC4(d0, a0.w, t3);
      ACC4(d1, a1.x, t0); ACC4(d1, a1.y, t1); ACC4(d1, a1.z, t2); ACC4(d1, a1.w, t3);
#undef ACC4
    }
    s0 += expf(10.f * d0.x) + expf(10.f * d0.y) + expf(10.f * d0.z) + expf(10.f * d0.w);
    s1 += expf(10.f * d1.x) + expf(10.f * d1.y) + expf(10.f * d1.z) + expf(10.f * d1.w);
  }
  // reduce across the 32 lanes of each half-wave (one pair group)
#pragma unroll
  for (int m = 16; m > 0; m >>= 1) {
    s0 += __shfl_xor(s0, m);
    s1 += __shfl_xor(s1, m);
  }
  if (cg == 0) {
    atomicAdd(&acc[(pb + p0) & 255], logf(s0));
    atomicAdd(&acc[(pb + p1) & 255], logf(s1));
  }
}

// ---------------- finalize scalars ----------------
__global__ __launch_bounds__(256) void finalize_kernel(const float* __restrict__ acc,
                                                       float* __restrict__ out) {
  const int t = threadIdx.x;
  float vq = acc[t], qd = acc[256 + t], tr = acc[512 + t], ou = acc[768 + t];
#pragma unroll
  for (int m = 32; m > 0; m >>= 1) {
    vq += __shfl_xor(vq, m);
    qd += __shfl_xor(qd, m);
    tr += __shfl_xor(tr, m);
    ou += __shfl_xor(ou, m);
  }
  __shared__ float sm[4][4];
  const int w = t >> 6;
  if ((t & 63) == 0) { sm[0][w] = vq; sm[1][w] = qd; sm[2][w] = tr; sm[3][w] = ou; }
  __syncthreads();
  if (t == 0) {
    float svq = sm[0][0] + sm[0][1] + sm[0][2] + sm[0][3];
    float sqd = sm[1][0] + sm[1][1] + sm[1][2] + sm[1][3];
    float str = sm[2][0] + sm[2][1] + sm[2][2] + sm[2][3];
    float sou = sm[3][0] + sm[3][1] + sm[3][2] + sm[3][3];
    out[OFF_VQ]  = 1.001f * svq / (float)((size_t)kN * kE);   // (1+beta)*mean
    out[OFF_OCL] = sou / (float)kKP;
    out[OFF_ITL] = str / (float)kTT;
    out[OFF_QDA] = 1.f - sqd / (float)kN;
  }
}

// ---------------- orchestration ----------------
extern "C" void kernel_launch(void* const* d_in, const int* in_sizes, int n_in,
                              void* d_out, int out_size, void* d_ws, size_t ws_size,
                              hipStream_t stream) {
  (void)in_sizes; (void)n_in; (void)out_size; (void)ws_size;
  const float* x    = (const float*)d_in[0];
  const float* qe   = (const float*)d_in[1];
  const float* qdw  = (const float*)d_in[2];
  const int*   prs  = (const int*)d_in[3];
  const int*   trs  = (const int*)d_in[4];
  const float* ew0  = (const float*)d_in[5];
  const float* eb0  = (const float*)d_in[6];
  const float* ew1  = (const float*)d_in[7];
  const float* eb1  = (const float*)d_in[8];
  const float* ew2  = (const float*)d_in[9];
  const float* eb2  = (const float*)d_in[10];
  const float* dw0  = (const float*)d_in[11];
  const float* db0  = (const float*)d_in[12];
  const float* dw1  = (const float*)d_in[13];
  const float* db1  = (const float*)d_in[14];
  const float* dw2  = (const float*)d_in[15];
  const float* db2  = (const float*)d_in[16];
  const float* cb   = (const float*)d_in[17];
  float* out = (float*)d_out;

  float* z   = (float*)d_ws;                       // N x E
  float* qz  = z  + (size_t)kN * kE;               // N x E
  float* xn  = qz + (size_t)kN * kE;               // N x E
  float* h1  = xn + (size_t)kN * kE;               // Chunk x H1
  float* h2  = h1 + (size_t)kChunk * kH1;          // Chunk x H2
  float* acc = h2 + (size_t)kChunk * kH2;          // 1024 accumulator slots

  hipMemsetAsync(acc, 0, 1024 * sizeof(float), stream);

  // encoder on x -> z, and on q_embs -> qz (chunked over rows)
  for (int c = 0; c < kN / kChunk; ++c) {
    const float* xc = x + (size_t)c * kChunk * kIN;
    sgemm<128, 128, 16, 8, 8, true><<<dim3(kH1 / 128, kChunk / 128), 256, 0, stream>>>(
        xc, ew0, eb0, h1, kChunk, kH1, kIN);
    sgemm<128, 128, 16, 8, 8, true><<<dim3(kH2 / 128, kChunk / 128), 256, 0, stream>>>(
        h1, ew1, eb1, h2, kChunk, kH2, kH1);
    sgemm<64, 64, 16, 4, 4, false><<<dim3(kE / 64, kChunk / 64), 256, 0, stream>>>(
        h2, ew2, eb2, z + (size_t)c * kChunk * kE, kChunk, kE, kH2);

    const float* qc = qe + (size_t)c * kChunk * kIN;
    sgemm<128, 128, 16, 8, 8, true><<<dim3(kH1 / 128, kChunk / 128), 256, 0, stream>>>(
        qc, ew0, eb0, h1, kChunk, kH1, kIN);
    sgemm<128, 128, 16, 8, 8, true><<<dim3(kH2 / 128, kChunk / 128), 256, 0, stream>>>(
        h1, ew1, eb1, h2, kChunk, kH2, kH1);
    sgemm<64, 64, 16, 4, 4, false><<<dim3(kE / 64, kChunk / 64), 256, 0, stream>>>(
        h2, ew2, eb2, qz + (size_t)c * kChunk * kE, kChunk, kE, kH2);
  }

  // VQ: idx (as float), x_q_st = codebook[idx], xn = normalized, vq partial sums
  vq_kernel<<<kN, 256, 0, stream>>>(z, cb, out + OFF_IDX, out + OFF_XQ, xn, acc);

  // decoder on x_q_st -> out (chunked)
  for (int c = 0; c < kN / kChunk; ++c) {
    const float* xqc = out + OFF_XQ + (size_t)c * kChunk * kE;
    sgemm<128, 128, 16, 8, 8, true><<<dim3(kH2 / 128, kChunk / 128), 256, 0, stream>>>(
        xqc, dw0, db0, h2, kChunk, kH2, kE);
    sgemm<128, 128, 16, 8, 8, true><<<dim3(kH1 / 128, kChunk / 128), 256, 0, stream>>>(
        h2, dw1, db1, h1, kChunk, kH1, kH2);
    sgemm<128, 128, 16, 8, 8, false><<<dim3(kIN / 128, kChunk / 128), 256, 0, stream>>>(
        h1, dw2, db2, out + OFF_OUT + (size_t)c * kChunk * kIN, kChunk, kIN, kH1);
  }

  // small loss kernels
  qd_kernel<<<kN / 4, 256, 0, stream>>>(z, qz, qdw, acc + 256);
  trip_kernel<<<kTT / 4, 256, 0, stream>>>(z, trs, acc + 512);
  pos_kernel<<<kKP / 4, 256, 0, stream>>>(xn, prs, acc + 768);
  lse_kernel<<<kKP / 16, 256, 0, stream>>>(xn, prs, acc + 768);

  finalize_kernel<<<1, 256, 0, stream>>>(acc, out);
}

// Round 2
// 5300.164 us; speedup vs baseline: 2.4217x; 2.4217x over previous
//
#include <hip/hip_runtime.h>
#include <hip/hip_bf16.h>

// ---------------- problem constants ----------------
namespace {
constexpr int kN = 32768, kIN = 768, kH1 = 2048, kH2 = 1024, kE = 64, kNE = 256;
constexpr int kKP = 4096, kTT = 8192;
constexpr int kChunk = 4096;   // rows per fp32 GEMM slice
constexpr int kChunkB = 8192;  // rows per bf16 GEMM slice

// flat float32 offsets in d_out, reference return order
constexpr size_t OFF_OUT = 0;
constexpr size_t OFF_VQ  = (size_t)kN * kIN;
constexpr size_t OFF_IDX = OFF_VQ + 1;
constexpr size_t OFF_XQ  = OFF_IDX + (size_t)kN;
constexpr size_t OFF_OCL = OFF_XQ + (size_t)kN * kE;
constexpr size_t OFF_ITL = OFF_OCL + 1;
constexpr size_t OFF_QDA = OFF_ITL + 1;
}  // namespace

typedef short bf16x8 __attribute__((ext_vector_type(8)));
typedef float f32x4 __attribute__((ext_vector_type(4)));

__device__ __forceinline__ unsigned short f2bf(float v) {
  __hip_bfloat16 h = __float2bfloat16(v);
  return *reinterpret_cast<unsigned short*>(&h);
}

__device__ __forceinline__ void gload_lds16(const void* g, void* lds) {
  __builtin_amdgcn_global_load_lds(
      (const __attribute__((address_space(1))) void*)g,
      (__attribute__((address_space(3))) void*)lds, 16, 0, 0);
}

// ---------------- fp32 tiled GEMM (x-encoder path): C = relu?(A@B + bias) ----
template <int BM, int BN, int BK, int TM, int TN, bool RELU>
__global__ __launch_bounds__(256) void sgemm(const float* __restrict__ A,
                                             const float* __restrict__ B,
                                             const float* __restrict__ bias,
                                             float* __restrict__ C,
                                             int M, int N, int K) {
  __shared__ float As[BK][BM];
  __shared__ float Bs[BK][BN];
  const int tid = threadIdx.x;
  const int col0 = blockIdx.x * BN;
  const int row0 = blockIdx.y * BM;
  const int tx = tid % (BN / TN);
  const int ty = tid / (BN / TN);
  float acc[TM][TN];
#pragma unroll
  for (int m = 0; m < TM; ++m)
#pragma unroll
    for (int n = 0; n < TN; ++n) acc[m][n] = 0.f;

  constexpr int ALOADS = (BM * BK) / (4 * 256);
  constexpr int BLOADS = (BK * BN) / (4 * 256);

  for (int k0 = 0; k0 < K; k0 += BK) {
#pragma unroll
    for (int i = 0; i < ALOADS; ++i) {
      int q = tid + 256 * i;
      int r = q / (BK / 4);
      int c4 = (q % (BK / 4)) * 4;
      float4 v = *(const float4*)(A + (size_t)(row0 + r) * K + k0 + c4);
      As[c4 + 0][r] = v.x;
      As[c4 + 1][r] = v.y;
      As[c4 + 2][r] = v.z;
      As[c4 + 3][r] = v.w;
    }
#pragma unroll
    for (int i = 0; i < BLOADS; ++i) {
      int q = tid + 256 * i;
      int r = q / (BN / 4);
      int c4 = (q % (BN / 4)) * 4;
      *(float4*)(&Bs[r][c4]) = *(const float4*)(B + (size_t)(k0 + r) * N + col0 + c4);
    }
    __syncthreads();
#pragma unroll
    for (int k = 0; k < BK; ++k) {
      float a[TM], b[TN];
#pragma unroll
      for (int m = 0; m < TM; m += 4)
        *(float4*)(&a[m]) = *(const float4*)(&As[k][ty * TM + m]);
#pragma unroll
      for (int n = 0; n < TN; n += 4)
        *(float4*)(&b[n]) = *(const float4*)(&Bs[k][tx * TN + n]);
#pragma unroll
      for (int m = 0; m < TM; ++m)
#pragma unroll
        for (int n = 0; n < TN; ++n) acc[m][n] = fmaf(a[m], b[n], acc[m][n]);
    }
    __syncthreads();
  }
#pragma unroll
  for (int m = 0; m < TM; ++m) {
    size_t r = (size_t)row0 + ty * TM + m;
#pragma unroll
    for (int n = 0; n < TN; ++n) {
      int c = col0 + tx * TN + n;
      float v = acc[m][n] + bias[c];
      if (RELU) v = fmaxf(v, 0.f);
      C[r * N + c] = v;
    }
  }
}

// ---------------- bf16 MFMA GEMM: C = relu?(A @ Bt^T + bias) ----------------
// A: MxK bf16 row-major. Bt: NxK bf16 row-major (weights pre-transposed).
// 256 threads = 4 waves in 2x2; each wave (BM/2)x(BN/2); 16x16x32 MFMA.
template <int BM, int BN, int BK, bool RELU, bool OUTF, bool OUTB>
__global__ __launch_bounds__(256) void gemm_bt(const unsigned short* __restrict__ A,
                                               const unsigned short* __restrict__ Bt,
                                               const float* __restrict__ bias,
                                               float* __restrict__ Cf,
                                               unsigned short* __restrict__ Cb,
                                               int N, int K) {
  constexpr int WM = BM / 2, WN = BN / 2, TMt = WM / 16, TNt = WN / 16;
  constexpr int CH = BK / 8;  // 16B chunks per LDS row (XOR-swizzle modulus)
  constexpr int RA = BM * BK / 2048, RB = BN * BK / 2048;
  __shared__ unsigned short As[BM * BK];
  __shared__ unsigned short Bs[BN * BK];
  const int tid = threadIdx.x, lane = tid & 63, wave = tid >> 6;
  const int wm = (wave >> 1) * WM, wn = (wave & 1) * WN;
  const int l15 = lane & 15, quad = lane >> 4;
  const int rowA0 = blockIdx.y * BM, colB0 = blockIdx.x * BN;
  f32x4 acc[TMt][TNt];
#pragma unroll
  for (int i = 0; i < TMt; ++i)
#pragma unroll
    for (int j = 0; j < TNt; ++j) acc[i][j] = (f32x4){0.f, 0.f, 0.f, 0.f};

  const char* Ab = (const char*)A;
  const char* Bb = (const char*)Bt;
  char* AsB = (char*)As;
  char* BsB = (char*)Bs;

  for (int k0 = 0; k0 < K; k0 += BK) {
    if (k0) __syncthreads();
#pragma unroll
    for (int r = 0; r < RA; ++r) {
      int off = (r * 256 + tid) * 16;
      int row = off / (BK * 2);
      int sc = ((off >> 4) ^ row) & (CH - 1);
      gload_lds16(Ab + (size_t)(rowA0 + row) * (K * 2) + (size_t)k0 * 2 + sc * 16,
                  AsB + off);
    }
#pragma unroll
    for (int r = 0; r < RB; ++r) {
      int off = (r * 256 + tid) * 16;
      int row = off / (BK * 2);
      int sc = ((off >> 4) ^ row) & (CH - 1);
      gload_lds16(Bb + (size_t)(colB0 + row) * (K * 2) + (size_t)k0 * 2 + sc * 16,
                  BsB + off);
    }
    __syncthreads();
#pragma unroll
    for (int ks = 0; ks < BK; ks += 32) {
      bf16x8 af[TMt], bfr[TNt];
#pragma unroll
      for (int i = 0; i < TMt; ++i) {
        int row = wm + i * 16 + l15;
        int c = (((ks >> 3) + quad) ^ row) & (CH - 1);
        af[i] = *(const bf16x8*)(AsB + row * (BK * 2) + c * 16);
      }
#pragma unroll
      for (int j = 0; j < TNt; ++j) {
        int col = wn + j * 16 + l15;
        int c = (((ks >> 3) + quad) ^ col) & (CH - 1);
        bfr[j] = *(const bf16x8*)(BsB + col * (BK * 2) + c * 16);
      }
#pragma unroll
      for (int i = 0; i < TMt; ++i)
#pragma unroll
        for (int j = 0; j < TNt; ++j)
          acc[i][j] = __builtin_amdgcn_mfma_f32_16x16x32_bf16(af[i], bfr[j],
                                                              acc[i][j], 0, 0, 0);
    }
  }
  // epilogue: C/D layout col=lane&15, row=quad*4+reg
#pragma unroll
  for (int j = 0; j < TNt; ++j) {
    int col = colB0 + wn + j * 16 + l15;
    float bv = bias[col];
#pragma unroll
    for (int i = 0; i < TMt; ++i) {
      int rbase = rowA0 + wm + i * 16 + quad * 4;
#pragma unroll
      for (int r = 0; r < 4; ++r) {
        float v = acc[i][j][r] + bv;
        if (RELU) v = fmaxf(v, 0.f);
        size_t o = (size_t)(rbase + r) * N + col;
        if (OUTF) Cf[o] = v;
        if (OUTB) Cb[o] = f2bf(v);
      }
    }
  }
}

// ---------------- weight transpose fp32 KxN -> bf16 NxK ----------------
__global__ __launch_bounds__(256) void transpose_bf16(const float* __restrict__ W,
                                                      unsigned short* __restrict__ Wt,
                                                      int K, int N) {
  __shared__ float t[32][33];
  int bx = blockIdx.x * 32, by = blockIdx.y * 32;
  int tx = threadIdx.x & 31, ty = threadIdx.x >> 5;
#pragma unroll
  for (int i = 0; i < 32; i += 8)
    t[ty + i][tx] = W[(size_t)(by + ty + i) * N + bx + tx];
  __syncthreads();
#pragma unroll
  for (int i = 0; i < 32; i += 8)
    Wt[(size_t)(bx + ty + i) * K + by + tx] = f2bf(t[tx][ty + i]);
}

// ---------------- fp32 -> bf16 convert ----------------
__global__ __launch_bounds__(256) void conv_bf16(const float* __restrict__ in,
                                                 unsigned short* __restrict__ out,
                                                 int n4) {
  int i = (blockIdx.x * 256 + threadIdx.x);
  if (i < n4) {
    float4 v = *(const float4*)(in + (size_t)i * 4);
    unsigned short o[4] = {f2bf(v.x), f2bf(v.y), f2bf(v.z), f2bf(v.w)};
    *(uint2*)(out + (size_t)i * 4) = *(uint2*)o;
  }
}

// ---------------- VQ: argmin over 256 codes ----------------
__global__ __launch_bounds__(256) void vq_kernel(const float* __restrict__ z,
                                                 const float* __restrict__ cb,
                                                 float* __restrict__ idx_out,
                                                 float* __restrict__ xq_out,
                                                 unsigned short* __restrict__ xqb_out,
                                                 float* __restrict__ xn_out,
                                                 float* __restrict__ acc) {
  __shared__ float zs[kE];
  __shared__ float rv[256];
  __shared__ int ri[256];
  const int i = blockIdx.x;
  const int t = threadIdx.x;
  if (t < kE) zs[t] = z[(size_t)i * kE + t];
  __syncthreads();
  float dot = 0.f, nrm = 0.f;
  const float* c = cb + (size_t)t * kE;
#pragma unroll 8
  for (int e = 0; e < kE; ++e) {
    float ce = c[e];
    dot = fmaf(zs[e], ce, dot);
    nrm = fmaf(ce, ce, nrm);
  }
  rv[t] = nrm - 2.f * dot;
  ri[t] = t;
  __syncthreads();
  for (int s = 128; s > 0; s >>= 1) {
    if (t < s) {
      float v2 = rv[t + s];
      int i2 = ri[t + s];
      if (v2 < rv[t] || (v2 == rv[t] && i2 < ri[t])) { rv[t] = v2; ri[t] = i2; }
    }
    __syncthreads();
  }
  const int best = ri[0];
  if (t == 0) idx_out[i] = (float)best;
  if (t < kE) {
    float xq = cb[(size_t)best * kE + t];
    xq_out[(size_t)i * kE + t] = xq;
    xqb_out[(size_t)i * kE + t] = f2bf(xq);
    float d = xq - zs[t];
    float sq = d * d;
    float nq = xq * xq;
#pragma unroll
    for (int m = 32; m > 0; m >>= 1) {
      sq += __shfl_xor(sq, m);
      nq += __shfl_xor(nq, m);
    }
    float inv = 1.f / fmaxf(sqrtf(nq), 1e-12f);
    xn_out[(size_t)i * kE + t] = xq * inv;
    if (t == 0) atomicAdd(&acc[i & 255], sq);
  }
}

// ---------------- qd_align ----------------
__global__ __launch_bounds__(256) void qd_kernel(const float* __restrict__ z,
                                                 const float* __restrict__ qz,
                                                 const float* __restrict__ w,
                                                 float* __restrict__ acc) {
  const int i = blockIdx.x * 4 + (threadIdx.x >> 6);
  const int l = threadIdx.x & 63;
  float a = z[(size_t)i * kE + l];
  float b = qz[(size_t)i * kE + l];
  float dot = a * b, na = a * a, nb = b * b;
#pragma unroll
  for (int m = 32; m > 0; m >>= 1) {
    dot += __shfl_xor(dot, m);
    na += __shfl_xor(na, m);
    nb += __shfl_xor(nb, m);
  }
  if (l == 0) {
    float cosv = dot / fmaxf(sqrtf(na) * sqrtf(nb), 1e-8f);
    atomicAdd(&acc[i & 255], w[i] * cosv);
  }
}

// ---------------- triplet ----------------
__global__ __launch_bounds__(256) void trip_kernel(const float* __restrict__ z,
                                                   const int* __restrict__ tr,
                                                   float* __restrict__ acc) {
  const int t = blockIdx.x * 4 + (threadIdx.x >> 6);
  const int l = threadIdx.x & 63;
  int ia = tr[3 * t], ip = tr[3 * t + 1], in2 = tr[3 * t + 2];
  float a = z[(size_t)ia * kE + l];
  float p = z[(size_t)ip * kE + l];
  float n = z[(size_t)in2 * kE + l];
  float d1 = (a - p) * (a - p);
  float d2 = (a - n) * (a - n);
#pragma unroll
  for (int m = 32; m > 0; m >>= 1) {
    d1 += __shfl_xor(d1, m);
    d2 += __shfl_xor(d2, m);
  }
  if (l == 0) {
    float dp = sqrtf(d1 + 1e-12f);
    float dn = sqrtf(d2 + 1e-12f);
    atomicAdd(&acc[t & 255], fmaxf(dp - dn + 0.2f, 0.f));
  }
}

// ---------------- pairs: subtract positive sim ----------------
__global__ __launch_bounds__(256) void pos_kernel(const float* __restrict__ xn,
                                                  const int* __restrict__ pairs,
                                                  float* __restrict__ acc) {
  const int k = blockIdx.x * 4 + (threadIdx.x >> 6);
  const int l = threadIdx.x & 63;
  int i0 = pairs[2 * k], i1 = pairs[2 * k + 1];
  float v = xn[(size_t)i0 * kE + l] * xn[(size_t)i1 * kE + l];
#pragma unroll
  for (int m = 32; m > 0; m >>= 1) v += __shfl_xor(v, m);
  if (l == 0) atomicAdd(&acc[k & 255], -10.f * v);
}

// ---------------- pairs: partial sumexp over a j-segment ----------------
// grid (kKP/16, 8): 16 pairs per block, kN/8 columns per segment.
__global__ __launch_bounds__(256) void lse_kernel(const float* __restrict__ xn,
                                                  const int* __restrict__ pairs,
                                                  float* __restrict__ pairsum) {
  constexpr int PPB = 16, TJ = 128, PAD = 4, JSEG = kN / 8;
  __shared__ float anch[PPB][kE];
  __shared__ float tileT[kE][TJ + PAD];
  const int t = threadIdx.x;
  const int pb = blockIdx.x * PPB;
  const int jbase = blockIdx.y * JSEG;
  for (int q = t; q < PPB * kE; q += 256) {
    int p = q >> 6, e = q & 63;
    anch[p][e] = xn[(size_t)pairs[2 * (pb + p)] * kE + e];
  }
  const int cg = t & 31;
  const int pg = t >> 5;
  const int c0 = cg * 4;
  const int p0 = 2 * pg, p1 = 2 * pg + 1;
  const int cload = t & 127;
  const int eb = t >> 7;
  float s0 = 0.f, s1 = 0.f;
  for (int j0 = jbase; j0 < jbase + JSEG; j0 += TJ) {
    __syncthreads();
#pragma unroll
    for (int i = 0; i < 8; ++i) {
      int e4 = (eb + 2 * i) * 4;
      float4 v = *(const float4*)(xn + (size_t)(j0 + cload) * kE + e4);
      tileT[e4 + 0][cload] = v.x;
      tileT[e4 + 1][cload] = v.y;
      tileT[e4 + 2][cload] = v.z;
      tileT[e4 + 3][cload] = v.w;
    }
    __syncthreads();
    float4 d0 = {0.f, 0.f, 0.f, 0.f}, d1 = {0.f, 0.f, 0.f, 0.f};
#pragma unroll
    for (int e = 0; e < kE; e += 4) {
      float4 a0 = *(const float4*)(&anch[p0][e]);
      float4 a1 = *(const float4*)(&anch[p1][e]);
      float4 t0 = *(const float4*)(&tileT[e + 0][c0]);
      float4 t1 = *(const float4*)(&tileT[e + 1][c0]);
      float4 t2 = *(const float4*)(&tileT[e + 2][c0]);
      float4 t3 = *(const float4*)(&tileT[e + 3][c0]);
#define ACC4(dd, aa, tt)              \
  dd.x = fmaf(aa, tt.x, dd.x);        \
  dd.y = fmaf(aa, tt.y, dd.y);        \
  dd.z = fmaf(aa, tt.z, dd.z);        \
  dd.w = fmaf(aa, tt.w, dd.w)
      ACC4(d0, a0.x, t0); ACC4(d0, a0.y, t1); ACC4(d0, a0.z, t2); ACC4(d0, a0.w, t3);
      ACC4(d1, a1.x, t0); ACC4(d1, a1.y, t1); ACC4(d1, a1.z, t2); ACC4(d1, a1.w, t3);
#undef ACC4
    }
    s0 += expf(10.f * d0.x) + expf(10.f * d0.y) + expf(10.f * d0.z) + expf(10.f * d0.w);
    s1 += expf(10.f * d1.x) + expf(10.f * d1.y) + expf(10.f * d1.z) + expf(10.f * d1.w);
  }
#pragma unroll
  for (int m = 16; m > 0; m >>= 1) {
    s0 += __shfl_xor(s0, m);
    s1 += __shfl_xor(s1, m);
  }
  if (cg == 0) {
    atomicAdd(&pairsum[pb + p0], s0);
    atomicAdd(&pairsum[pb + p1], s1);
  }
}

__global__ __launch_bounds__(256) void lse_log_kernel(const float* __restrict__ pairsum,
                                                      float* __restrict__ acc) {
  int p = blockIdx.x * 256 + threadIdx.x;
  atomicAdd(&acc[p & 255], logf(pairsum[p]));
}

// ---------------- finalize scalars ----------------
__global__ __launch_bounds__(256) void finalize_kernel(const float* __restrict__ acc,
                                                       float* __restrict__ out) {
  const int t = threadIdx.x;
  float vq = acc[t], qd = acc[256 + t], tr = acc[512 + t], ou = acc[768 + t];
#pragma unroll
  for (int m = 32; m > 0; m >>= 1) {
    vq += __shfl_xor(vq, m);
    qd += __shfl_xor(qd, m);
    tr += __shfl_xor(tr, m);
    ou += __shfl_xor(ou, m);
  }
  __shared__ float sm[4][4];
  const int w = t >> 6;
  if ((t & 63) == 0) { sm[0][w] = vq; sm[1][w] = qd; sm[2][w] = tr; sm[3][w] = ou; }
  __syncthreads();
  if (t == 0) {
    float svq = sm[0][0] + sm[0][1] + sm[0][2] + sm[0][3];
    float sqd = sm[1][0] + sm[1][1] + sm[1][2] + sm[1][3];
    float str = sm[2][0] + sm[2][1] + sm[2][2] + sm[2][3];
    float sou = sm[3][0] + sm[3][1] + sm[3][2] + sm[3][3];
    out[OFF_VQ]  = 1.001f * svq / (float)((size_t)kN * kE);
    out[OFF_OCL] = sou / (float)kKP;
    out[OFF_ITL] = str / (float)kTT;
    out[OFF_QDA] = 1.f - sqd / (float)kN;
  }
}

// ---------------- orchestration ----------------
extern "C" void kernel_launch(void* const* d_in, const int* in_sizes, int n_in,
                              void* d_out, int out_size, void* d_ws, size_t ws_size,
                              hipStream_t stream) {
  (void)in_sizes; (void)n_in; (void)out_size; (void)ws_size;
  const float* x    = (const float*)d_in[0];
  const float* qe   = (const float*)d_in[1];
  const float* qdw  = (const float*)d_in[2];
  const int*   prs  = (const int*)d_in[3];
  const int*   trs  = (const int*)d_in[4];
  const float* ew0  = (const float*)d_in[5];
  const float* eb0  = (const float*)d_in[6];
  const float* ew1  = (const float*)d_in[7];
  const float* eb1  = (const float*)d_in[8];
  const float* ew2  = (const float*)d_in[9];
  const float* eb2  = (const float*)d_in[10];
  const float* dw0  = (const float*)d_in[11];
  const float* db0  = (const float*)d_in[12];
  const float* dw1  = (const float*)d_in[13];
  const float* db1  = (const float*)d_in[14];
  const float* dw2  = (const float*)d_in[15];
  const float* db2  = (const float*)d_in[16];
  const float* cb   = (const float*)d_in[17];
  float* out = (float*)d_out;

  // ---- workspace carve-up (~107 MB) ----
  float* z   = (float*)d_ws;                         // N x E fp32
  float* qz  = z  + (size_t)kN * kE;
  float* xn  = qz + (size_t)kN * kE;
  float* S1  = xn + (size_t)kN * kE;                 // 8,388,608 f (32 MB)
  float* S2  = S1 + (size_t)8388608;                 // 4,194,304 f (16 MB)
  float* acc = S2 + (size_t)4194304;                 // 1024 f
  float* pairsum = acc + 1024;                       // 4096 f
  unsigned short* Sa  = (unsigned short*)(pairsum + 4096);  // 8192x768 bf16
  unsigned short* wt0 = Sa  + (size_t)8192 * 768;    // ew0t 2048x768
  unsigned short* wt1 = wt0 + (size_t)2048 * 768;    // ew1t 1024x2048
  unsigned short* wt2 = wt1 + (size_t)1024 * 2048;   // ew2t 64x1024
  unsigned short* wt3 = wt2 + (size_t)64 * 1024;     // dw0t 1024x64
  unsigned short* wt4 = wt3 + (size_t)1024 * 64;     // dw1t 2048x1024
  unsigned short* wt5 = wt4 + (size_t)2048 * 1024;   // dw2t 768x2048
  unsigned short* xqb = wt5 + (size_t)768 * 2048;    // N x E bf16

  hipMemsetAsync(acc, 0, (1024 + 4096) * sizeof(float), stream);

  // weight transposes fp32 KxN -> bf16 NxK
  transpose_bf16<<<dim3(kH1 / 32, kIN / 32), 256, 0, stream>>>(ew0, wt0, kIN, kH1);
  transpose_bf16<<<dim3(kH2 / 32, kH1 / 32), 256, 0, stream>>>(ew1, wt1, kH1, kH2);
  transpose_bf16<<<dim3(kE / 32, kH2 / 32), 256, 0, stream>>>(ew2, wt2, kH2, kE);
  transpose_bf16<<<dim3(kH2 / 32, kE / 32), 256, 0, stream>>>(dw0, wt3, kE, kH2);
  transpose_bf16<<<dim3(kH1 / 32, kH2 / 32), 256, 0, stream>>>(dw1, wt4, kH2, kH1);
  transpose_bf16<<<dim3(kIN / 32, kH1 / 32), 256, 0, stream>>>(dw2, wt5, kH1, kIN);

  // x-encoder (fp32, idx-critical) -> z
  for (int c = 0; c < kN / kChunk; ++c) {
    const float* xc = x + (size_t)c * kChunk * kIN;
    sgemm<128, 128, 16, 8, 8, true><<<dim3(kH1 / 128, kChunk / 128), 256, 0, stream>>>(
        xc, ew0, eb0, S1, kChunk, kH1, kIN);
    sgemm<128, 128, 16, 8, 8, true><<<dim3(kH2 / 128, kChunk / 128), 256, 0, stream>>>(
        S1, ew1, eb1, S2, kChunk, kH2, kH1);
    sgemm<64, 64, 16, 4, 4, false><<<dim3(kE / 64, kChunk / 64), 256, 0, stream>>>(
        S2, ew2, eb2, z + (size_t)c * kChunk * kE, kChunk, kE, kH2);
  }

  // VQ
  vq_kernel<<<kN, 256, 0, stream>>>(z, cb, out + OFF_IDX, out + OFF_XQ, xqb, xn, acc);

  // q-encoder (bf16 MFMA) -> qz
  for (int c = 0; c < kN / kChunkB; ++c) {
    conv_bf16<<<(kChunkB * kIN / 4 + 255) / 256, 256, 0, stream>>>(
        qe + (size_t)c * kChunkB * kIN, Sa, kChunkB * kIN / 4);
    gemm_bt<128, 128, 64, true, false, true>
        <<<dim3(kH1 / 128, kChunkB / 128), 256, 0, stream>>>(
            Sa, wt0, eb0, nullptr, (unsigned short*)S1, kH1, kIN);
    gemm_bt<128, 128, 64, true, false, true>
        <<<dim3(kH2 / 128, kChunkB / 128), 256, 0, stream>>>(
            (unsigned short*)S1, wt1, eb1, nullptr, (unsigned short*)S2, kH2, kH1);
    gemm_bt<128, 64, 64, false, true, false>
        <<<dim3(kE / 64, kChunkB / 128), 256, 0, stream>>>(
            (unsigned short*)S2, wt2, eb2, qz + (size_t)c * kChunkB * kE, nullptr,
            kE, kH2);
  }

  // decoder (bf16 MFMA) on x_q_st -> out
  for (int c = 0; c < kN / kChunkB; ++c) {
    gemm_bt<128, 128, 64, true, false, true>
        <<<dim3(kH2 / 128, kChunkB / 128), 256, 0, stream>>>(
            xqb + (size_t)c * kChunkB * kE, wt3, db0, nullptr, (unsigned short*)S2,
            kH2, kE);
    gemm_bt<128, 128, 64, true, false, true>
        <<<dim3(kH1 / 128, kChunkB / 128), 256, 0, stream>>>(
            (unsigned short*)S2, wt4, db1, nullptr, (unsigned short*)S1, kH1, kH2);
    gemm_bt<128, 128, 64, false, true, false>
        <<<dim3(kIN / 128, kChunkB / 128), 256, 0, stream>>>(
            (unsigned short*)S1, wt5, db2, out + OFF_OUT + (size_t)c * kChunkB * kIN,
            nullptr, kIN, kH1);
  }

  // small loss kernels
  qd_kernel<<<kN / 4, 256, 0, stream>>>(z, qz, qdw, acc + 256);
  trip_kernel<<<kTT / 4, 256, 0, stream>>>(z, trs, acc + 512);
  pos_kernel<<<kKP / 4, 256, 0, stream>>>(xn, prs, acc + 768);
  lse_kernel<<<dim3(kKP / 16, 8), 256, 0, stream>>>(xn, prs, pairsum);
  lse_log_kernel<<<kKP / 256, 256, 0, stream>>>(pairsum, acc + 768);

  finalize_kernel<<<1, 256, 0, stream>>>(acc, out);
}

// Round 3
// 3617.894 us; speedup vs baseline: 3.5477x; 1.4650x over previous
//
#include <hip/hip_runtime.h>
#include <hip/hip_bf16.h>

// ---------------- problem constants ----------------
namespace {
constexpr int kN = 32768, kIN = 768, kH1 = 2048, kH2 = 1024, kE = 64, kNE = 256;
constexpr int kKP = 4096, kTT = 8192;
constexpr int kCh = 4096;  // rows per GEMM slice

// flat float32 offsets in d_out, reference return order
constexpr size_t OFF_OUT = 0;
constexpr size_t OFF_VQ  = (size_t)kN * kIN;
constexpr size_t OFF_IDX = OFF_VQ + 1;
constexpr size_t OFF_XQ  = OFF_IDX + (size_t)kN;
constexpr size_t OFF_OCL = OFF_XQ + (size_t)kN * kE;
constexpr size_t OFF_ITL = OFF_OCL + 1;
constexpr size_t OFF_QDA = OFF_ITL + 1;
}  // namespace

typedef short bf16x8 __attribute__((ext_vector_type(8)));
typedef float f32x4 __attribute__((ext_vector_type(4)));

__device__ __forceinline__ unsigned short f2bf(float v) {
  __hip_bfloat16 h = __float2bfloat16(v);
  return *reinterpret_cast<unsigned short*>(&h);
}
__device__ __forceinline__ float bf2f(unsigned short u) {
  __hip_bfloat16 h = *reinterpret_cast<__hip_bfloat16*>(&u);
  return __bfloat162float(h);
}

__device__ __forceinline__ void gload_lds16(const void* g, void* lds) {
  __builtin_amdgcn_global_load_lds(
      (const __attribute__((address_space(1))) void*)g,
      (__attribute__((address_space(3))) void*)lds, 16, 0, 0);
}

// ---------------- bf16 MFMA GEMM: C = relu?(A @ Bt^T + bias) ----------------
// A: MxK bf16 row-major. Bt: NxK bf16 row-major. 4 waves in 2x2; 16x16x32 MFMA.
template <int BM, int BN, int BK, bool RELU, bool OUTF, bool OUTB>
__global__ __launch_bounds__(256) void gemm_bt(const unsigned short* __restrict__ A,
                                               const unsigned short* __restrict__ Bt,
                                               const float* __restrict__ bias,
                                               float* __restrict__ Cf,
                                               unsigned short* __restrict__ Cb,
                                               int N, int K) {
  constexpr int WM = BM / 2, WN = BN / 2, TMt = WM / 16, TNt = WN / 16;
  constexpr int CH = BK / 8;
  constexpr int RA = BM * BK / 2048, RB = BN * BK / 2048;
  __shared__ unsigned short As[BM * BK];
  __shared__ unsigned short Bs[BN * BK];
  const int tid = threadIdx.x, lane = tid & 63, wave = tid >> 6;
  const int wm = (wave >> 1) * WM, wn = (wave & 1) * WN;
  const int l15 = lane & 15, quad = lane >> 4;
  const int rowA0 = blockIdx.y * BM, colB0 = blockIdx.x * BN;
  f32x4 acc[TMt][TNt];
#pragma unroll
  for (int i = 0; i < TMt; ++i)
#pragma unroll
    for (int j = 0; j < TNt; ++j) acc[i][j] = (f32x4){0.f, 0.f, 0.f, 0.f};

  const char* Ab = (const char*)A;
  const char* Bb = (const char*)Bt;
  char* AsB = (char*)As;
  char* BsB = (char*)Bs;

  for (int k0 = 0; k0 < K; k0 += BK) {
    if (k0) __syncthreads();
#pragma unroll
    for (int r = 0; r < RA; ++r) {
      int off = (r * 256 + tid) * 16;
      int row = off / (BK * 2);
      int sc = ((off >> 4) ^ row) & (CH - 1);
      gload_lds16(Ab + (size_t)(rowA0 + row) * (K * 2) + (size_t)k0 * 2 + sc * 16,
                  AsB + off);
    }
#pragma unroll
    for (int r = 0; r < RB; ++r) {
      int off = (r * 256 + tid) * 16;
      int row = off / (BK * 2);
      int sc = ((off >> 4) ^ row) & (CH - 1);
      gload_lds16(Bb + (size_t)(colB0 + row) * (K * 2) + (size_t)k0 * 2 + sc * 16,
                  BsB + off);
    }
    __syncthreads();
#pragma unroll
    for (int ks = 0; ks < BK; ks += 32) {
      bf16x8 af[TMt], bfr[TNt];
#pragma unroll
      for (int i = 0; i < TMt; ++i) {
        int row = wm + i * 16 + l15;
        int c = (((ks >> 3) + quad) ^ row) & (CH - 1);
        af[i] = *(const bf16x8*)(AsB + row * (BK * 2) + c * 16);
      }
#pragma unroll
      for (int j = 0; j < TNt; ++j) {
        int col = wn + j * 16 + l15;
        int c = (((ks >> 3) + quad) ^ col) & (CH - 1);
        bfr[j] = *(const bf16x8*)(BsB + col * (BK * 2) + c * 16);
      }
#pragma unroll
      for (int i = 0; i < TMt; ++i)
#pragma unroll
        for (int j = 0; j < TNt; ++j)
          acc[i][j] = __builtin_amdgcn_mfma_f32_16x16x32_bf16(af[i], bfr[j],
                                                              acc[i][j], 0, 0, 0);
    }
  }
#pragma unroll
  for (int j = 0; j < TNt; ++j) {
    int col = colB0 + wn + j * 16 + l15;
    float bv = bias[col];
#pragma unroll
    for (int i = 0; i < TMt; ++i) {
      int rbase = rowA0 + wm + i * 16 + quad * 4;
#pragma unroll
      for (int r = 0; r < 4; ++r) {
        float v = acc[i][j][r] + bv;
        if (RELU) v = fmaxf(v, 0.f);
        size_t o = (size_t)(rbase + r) * N + col;
        if (OUTF) Cf[o] = v;
        if (OUTB) Cb[o] = f2bf(v);
      }
    }
  }
}

// ---------------- split-bf16 MFMA GEMM (fp32-accurate x-path) ----------------
// C = relu?((Ah+Al) @ (Bh+Bl)^T + bias), dropping Al*Bl (err ~2^-18).
// OM: 0 = write fp32 C; 2 = write split bf16 (Ch, Cl).
template <int BM, int BN, int BK, bool RELU, int OM>
__global__ __launch_bounds__(256) void gemm_bt_split(
    const unsigned short* __restrict__ Ah, const unsigned short* __restrict__ Al,
    const unsigned short* __restrict__ Bh, const unsigned short* __restrict__ Bl,
    const float* __restrict__ bias, float* __restrict__ Cf,
    unsigned short* __restrict__ Ch, unsigned short* __restrict__ Cl,
    int N, int K) {
  constexpr int WM = BM / 2, WN = BN / 2, TMt = WM / 16, TNt = WN / 16;
  constexpr int CH = BK / 8;
  constexpr int RA = BM * BK / 2048, RB = BN * BK / 2048;
  __shared__ unsigned short AsH[BM * BK];
  __shared__ unsigned short AsL[BM * BK];
  __shared__ unsigned short BsH[BN * BK];
  __shared__ unsigned short BsL[BN * BK];
  const int tid = threadIdx.x, lane = tid & 63, wave = tid >> 6;
  const int wm = (wave >> 1) * WM, wn = (wave & 1) * WN;
  const int l15 = lane & 15, quad = lane >> 4;
  const int rowA0 = blockIdx.y * BM, colB0 = blockIdx.x * BN;
  f32x4 acc[TMt][TNt];
#pragma unroll
  for (int i = 0; i < TMt; ++i)
#pragma unroll
    for (int j = 0; j < TNt; ++j) acc[i][j] = (f32x4){0.f, 0.f, 0.f, 0.f};

  const char* AhB = (const char*)Ah;
  const char* AlB = (const char*)Al;
  const char* BhB = (const char*)Bh;
  const char* BlB = (const char*)Bl;

  for (int k0 = 0; k0 < K; k0 += BK) {
    if (k0) __syncthreads();
#pragma unroll
    for (int r = 0; r < RA; ++r) {
      int off = (r * 256 + tid) * 16;
      int row = off / (BK * 2);
      int sc = ((off >> 4) ^ row) & (CH - 1);
      size_t go = (size_t)(rowA0 + row) * (K * 2) + (size_t)k0 * 2 + sc * 16;
      gload_lds16(AhB + go, (char*)AsH + off);
      gload_lds16(AlB + go, (char*)AsL + off);
    }
#pragma unroll
    for (int r = 0; r < RB; ++r) {
      int off = (r * 256 + tid) * 16;
      int row = off / (BK * 2);
      int sc = ((off >> 4) ^ row) & (CH - 1);
      size_t go = (size_t)(colB0 + row) * (K * 2) + (size_t)k0 * 2 + sc * 16;
      gload_lds16(BhB + go, (char*)BsH + off);
      gload_lds16(BlB + go, (char*)BsL + off);
    }
    __syncthreads();
#pragma unroll
    for (int ks = 0; ks < BK; ks += 32) {
      bf16x8 ah[TMt], al[TMt], bh[TNt], bl[TNt];
#pragma unroll
      for (int i = 0; i < TMt; ++i) {
        int row = wm + i * 16 + l15;
        int c = (((ks >> 3) + quad) ^ row) & (CH - 1);
        int off = row * (BK * 2) + c * 16;
        ah[i] = *(const bf16x8*)((const char*)AsH + off);
        al[i] = *(const bf16x8*)((const char*)AsL + off);
      }
#pragma unroll
      for (int j = 0; j < TNt; ++j) {
        int col = wn + j * 16 + l15;
        int c = (((ks >> 3) + quad) ^ col) & (CH - 1);
        int off = col * (BK * 2) + c * 16;
        bh[j] = *(const bf16x8*)((const char*)BsH + off);
        bl[j] = *(const bf16x8*)((const char*)BsL + off);
      }
#pragma unroll
      for (int i = 0; i < TMt; ++i)
#pragma unroll
        for (int j = 0; j < TNt; ++j) {
          acc[i][j] = __builtin_amdgcn_mfma_f32_16x16x32_bf16(ah[i], bh[j], acc[i][j], 0, 0, 0);
          acc[i][j] = __builtin_amdgcn_mfma_f32_16x16x32_bf16(ah[i], bl[j], acc[i][j], 0, 0, 0);
          acc[i][j] = __builtin_amdgcn_mfma_f32_16x16x32_bf16(al[i], bh[j], acc[i][j], 0, 0, 0);
        }
    }
  }
#pragma unroll
  for (int j = 0; j < TNt; ++j) {
    int col = colB0 + wn + j * 16 + l15;
    float bv = bias[col];
#pragma unroll
    for (int i = 0; i < TMt; ++i) {
      int rbase = rowA0 + wm + i * 16 + quad * 4;
#pragma unroll
      for (int r = 0; r < 4; ++r) {
        float v = acc[i][j][r] + bv;
        if (RELU) v = fmaxf(v, 0.f);
        size_t o = (size_t)(rbase + r) * N + col;
        if (OM == 0) {
          Cf[o] = v;
        } else {
          unsigned short hi = f2bf(v);
          Ch[o] = hi;
          Cl[o] = f2bf(v - bf2f(hi));
        }
      }
    }
  }
}

// ---------------- weight transpose fp32 KxN -> bf16 NxK (single) ------------
__global__ __launch_bounds__(256) void transpose_bf16(const float* __restrict__ W,
                                                      unsigned short* __restrict__ Wt,
                                                      int K, int N) {
  __shared__ float t[32][33];
  int bx = blockIdx.x * 32, by = blockIdx.y * 32;
  int tx = threadIdx.x & 31, ty = threadIdx.x >> 5;
#pragma unroll
  for (int i = 0; i < 32; i += 8)
    t[ty + i][tx] = W[(size_t)(by + ty + i) * N + bx + tx];
  __syncthreads();
#pragma unroll
  for (int i = 0; i < 32; i += 8)
    Wt[(size_t)(bx + ty + i) * K + by + tx] = f2bf(t[tx][ty + i]);
}

// ---------------- weight transpose fp32 KxN -> split bf16 NxK ---------------
__global__ __launch_bounds__(256) void transpose_bf16_split(
    const float* __restrict__ W, unsigned short* __restrict__ Wh,
    unsigned short* __restrict__ Wl, int K, int N) {
  __shared__ float t[32][33];
  int bx = blockIdx.x * 32, by = blockIdx.y * 32;
  int tx = threadIdx.x & 31, ty = threadIdx.x >> 5;
#pragma unroll
  for (int i = 0; i < 32; i += 8)
    t[ty + i][tx] = W[(size_t)(by + ty + i) * N + bx + tx];
  __syncthreads();
#pragma unroll
  for (int i = 0; i < 32; i += 8) {
    float v = t[tx][ty + i];
    unsigned short hi = f2bf(v);
    size_t o = (size_t)(bx + ty + i) * K + by + tx;
    Wh[o] = hi;
    Wl[o] = f2bf(v - bf2f(hi));
  }
}

// ---------------- fp32 -> bf16 convert (single) ----------------
__global__ __launch_bounds__(256) void conv_bf16(const float* __restrict__ in,
                                                 unsigned short* __restrict__ out,
                                                 int n4) {
  int i = (blockIdx.x * 256 + threadIdx.x);
  if (i < n4) {
    float4 v = *(const float4*)(in + (size_t)i * 4);
    unsigned short o[4] = {f2bf(v.x), f2bf(v.y), f2bf(v.z), f2bf(v.w)};
    *(uint2*)(out + (size_t)i * 4) = *(uint2*)o;
  }
}

// ---------------- fp32 -> split bf16 convert ----------------
__global__ __launch_bounds__(256) void conv_split(const float* __restrict__ in,
                                                  unsigned short* __restrict__ oh,
                                                  unsigned short* __restrict__ ol,
                                                  int n4) {
  int i = (blockIdx.x * 256 + threadIdx.x);
  if (i < n4) {
    float4 v = *(const float4*)(in + (size_t)i * 4);
    unsigned short h[4], l[4];
    float vv[4] = {v.x, v.y, v.z, v.w};
#pragma unroll
    for (int k = 0; k < 4; ++k) {
      h[k] = f2bf(vv[k]);
      l[k] = f2bf(vv[k] - bf2f(h[k]));
    }
    *(uint2*)(oh + (size_t)i * 4) = *(uint2*)h;
    *(uint2*)(ol + (size_t)i * 4) = *(uint2*)l;
  }
}

// ---------------- VQ: argmin over 256 codes + gap-flagging ----------------
__global__ __launch_bounds__(256) void vq_kernel(const float* __restrict__ z,
                                                 const float* __restrict__ cb,
                                                 float* __restrict__ idx_out,
                                                 float* __restrict__ xq_out,
                                                 unsigned short* __restrict__ xqb_out,
                                                 float* __restrict__ xn_out,
                                                 float* __restrict__ acc,
                                                 int* __restrict__ flags,
                                                 int* __restrict__ flagcnt) {
  __shared__ float zs[kE];
  __shared__ float dsv[256];
  __shared__ float rv[256];
  __shared__ int ri[256];
  __shared__ int defer;
  const int i = blockIdx.x;
  const int t = threadIdx.x;
  if (t < kE) zs[t] = z[(size_t)i * kE + t];
  __syncthreads();
  float dot = 0.f, nrm = 0.f, zn = 0.f;
  const float* c = cb + (size_t)t * kE;
#pragma unroll 8
  for (int e = 0; e < kE; ++e) {
    float ce = c[e];
    float ze = zs[e];
    dot = fmaf(ze, ce, dot);
    nrm = fmaf(ce, ce, nrm);
    zn = fmaf(ze, ze, zn);
  }
  float d = nrm - 2.f * dot;
  dsv[t] = d;
  rv[t] = d;
  ri[t] = t;
  __syncthreads();
  for (int s = 128; s > 0; s >>= 1) {
    if (t < s) {
      float v2 = rv[t + s];
      int i2 = ri[t + s];
      if (v2 < rv[t] || (v2 == rv[t] && i2 < ri[t])) { rv[t] = v2; ri[t] = i2; }
    }
    __syncthreads();
  }
  const int best = ri[0];
  const float d1 = rv[0];
  __syncthreads();
  // second-best value
  rv[t] = (t == best) ? 3.4e38f : dsv[t];
  __syncthreads();
  for (int s = 128; s > 0; s >>= 1) {
    if (t < s) rv[t] = fminf(rv[t], rv[t + s]);
    __syncthreads();
  }
  if (t == 0) {
    float tau = 5e-5f * sqrtf(zn);
    if (rv[0] - d1 < tau) {
      defer = 1;
      int slot = atomicAdd(flagcnt, 1);
      flags[slot] = i;
    } else {
      defer = 0;
    }
  }
  __syncthreads();
  if (defer) return;
  if (t == 0) idx_out[i] = (float)best;
  if (t < kE) {
    float xq = cb[(size_t)best * kE + t];
    xq_out[(size_t)i * kE + t] = xq;
    xqb_out[(size_t)i * kE + t] = f2bf(xq);
    float dd = xq - zs[t];
    float sq = dd * dd;
    float nq = xq * xq;
#pragma unroll
    for (int m = 32; m > 0; m >>= 1) {
      sq += __shfl_xor(sq, m);
      nq += __shfl_xor(nq, m);
    }
    float inv = 1.f / fmaxf(sqrtf(nq), 1e-12f);
    xn_out[(size_t)i * kE + t] = xq * inv;
    if (t == 0) atomicAdd(&acc[i & 255], sq);
  }
}

// ---------------- fix flagged rows: exact fp32 MLP + argmin ----------------
__global__ __launch_bounds__(256) void fix_rows(
    const float* __restrict__ x, const float* __restrict__ ew0,
    const float* __restrict__ eb0, const float* __restrict__ ew1,
    const float* __restrict__ eb1, const float* __restrict__ ew2,
    const float* __restrict__ eb2, const float* __restrict__ cb,
    const int* __restrict__ flags, const int* __restrict__ flagcnt,
    float* __restrict__ z, float* __restrict__ idx_out,
    float* __restrict__ xq_out, unsigned short* __restrict__ xqb_out,
    float* __restrict__ xn_out, float* __restrict__ acc) {
  __shared__ float xs[kIN];
  __shared__ float sh1[kH1];
  __shared__ float sh2[kH2];
  __shared__ float sred[256];
  __shared__ float szs[kE];
  __shared__ float rv[256];
  __shared__ int ri[256];
  const int t = threadIdx.x;
  const int cnt = *flagcnt;
  for (int fi = blockIdx.x; fi < cnt; fi += gridDim.x) {
    const int r = flags[fi];
    for (int q = t; q < kIN; q += 256) xs[q] = x[(size_t)r * kIN + q];
    __syncthreads();
    // h1 = relu(x @ ew0 + eb0): 8 outputs per thread
#pragma unroll
    for (int o = 0; o < kH1 / 256; ++o) {
      int j = t + 256 * o;
      float s = eb0[j];
      for (int k = 0; k < kIN; ++k) s = fmaf(xs[k], ew0[(size_t)k * kH1 + j], s);
      sh1[j] = fmaxf(s, 0.f);
    }
    __syncthreads();
    // h2 = relu(h1 @ ew1 + eb1): 4 outputs per thread
#pragma unroll
    for (int o = 0; o < kH2 / 256; ++o) {
      int j = t + 256 * o;
      float s = eb1[j];
      for (int k = 0; k < kH1; ++k) s = fmaf(sh1[k], ew1[(size_t)k * kH2 + j], s);
      sh2[j] = fmaxf(s, 0.f);
    }
    __syncthreads();
    // z: 64 outputs, 4 partial threads each
    {
      int j = t & 63, p = t >> 6;
      float s = 0.f;
      for (int k = p * 256; k < p * 256 + 256; ++k)
        s = fmaf(sh2[k], ew2[(size_t)k * kE + j], s);
      sred[t] = s;
      __syncthreads();
      if (t < kE) {
        float zv = sred[t] + sred[t + 64] + sred[t + 128] + sred[t + 192] + eb2[t];
        szs[t] = zv;
        z[(size_t)r * kE + t] = zv;
      }
      __syncthreads();
    }
    // argmin over codes
    {
      float dot = 0.f, nrm = 0.f;
      const float* c = cb + (size_t)t * kE;
#pragma unroll 8
      for (int e = 0; e < kE; ++e) {
        float ce = c[e];
        dot = fmaf(szs[e], ce, dot);
        nrm = fmaf(ce, ce, nrm);
      }
      rv[t] = nrm - 2.f * dot;
      ri[t] = t;
      __syncthreads();
      for (int s = 128; s > 0; s >>= 1) {
        if (t < s) {
          float v2 = rv[t + s];
          int i2 = ri[t + s];
          if (v2 < rv[t] || (v2 == rv[t] && i2 < ri[t])) { rv[t] = v2; ri[t] = i2; }
        }
        __syncthreads();
      }
      const int best = ri[0];
      if (t == 0) idx_out[r] = (float)best;
      if (t < kE) {
        float xq = cb[(size_t)best * kE + t];
        xq_out[(size_t)r * kE + t] = xq;
        xqb_out[(size_t)r * kE + t] = f2bf(xq);
        float dd = xq - szs[t];
        float sq = dd * dd;
        float nq = xq * xq;
#pragma unroll
        for (int m = 32; m > 0; m >>= 1) {
          sq += __shfl_xor(sq, m);
          nq += __shfl_xor(nq, m);
        }
        float inv = 1.f / fmaxf(sqrtf(nq), 1e-12f);
        xn_out[(size_t)r * kE + t] = xq * inv;
        if (t == 0) atomicAdd(&acc[r & 255], sq);
      }
      __syncthreads();
    }
  }
}

// ---------------- qd_align ----------------
__global__ __launch_bounds__(256) void qd_kernel(const float* __restrict__ z,
                                                 const float* __restrict__ qz,
                                                 const float* __restrict__ w,
                                                 float* __restrict__ acc) {
  const int i = blockIdx.x * 4 + (threadIdx.x >> 6);
  const int l = threadIdx.x & 63;
  float a = z[(size_t)i * kE + l];
  float b = qz[(size_t)i * kE + l];
  float dot = a * b, na = a * a, nb = b * b;
#pragma unroll
  for (int m = 32; m > 0; m >>= 1) {
    dot += __shfl_xor(dot, m);
    na += __shfl_xor(na, m);
    nb += __shfl_xor(nb, m);
  }
  if (l == 0) {
    float cosv = dot / fmaxf(sqrtf(na) * sqrtf(nb), 1e-8f);
    atomicAdd(&acc[i & 255], w[i] * cosv);
  }
}

// ---------------- triplet ----------------
__global__ __launch_bounds__(256) void trip_kernel(const float* __restrict__ z,
                                                   const int* __restrict__ tr,
                                                   float* __restrict__ acc) {
  const int t = blockIdx.x * 4 + (threadIdx.x >> 6);
  const int l = threadIdx.x & 63;
  int ia = tr[3 * t], ip = tr[3 * t + 1], in2 = tr[3 * t + 2];
  float a = z[(size_t)ia * kE + l];
  float p = z[(size_t)ip * kE + l];
  float n = z[(size_t)in2 * kE + l];
  float d1 = (a - p) * (a - p);
  float d2 = (a - n) * (a - n);
#pragma unroll
  for (int m = 32; m > 0; m >>= 1) {
    d1 += __shfl_xor(d1, m);
    d2 += __shfl_xor(d2, m);
  }
  if (l == 0) {
    float dp = sqrtf(d1 + 1e-12f);
    float dn = sqrtf(d2 + 1e-12f);
    atomicAdd(&acc[t & 255], fmaxf(dp - dn + 0.2f, 0.f));
  }
}

// ---------------- pairs: subtract positive sim ----------------
__global__ __launch_bounds__(256) void pos_kernel(const float* __restrict__ xn,
                                                  const int* __restrict__ pairs,
                                                  float* __restrict__ acc) {
  const int k = blockIdx.x * 4 + (threadIdx.x >> 6);
  const int l = threadIdx.x & 63;
  int i0 = pairs[2 * k], i1 = pairs[2 * k + 1];
  float v = xn[(size_t)i0 * kE + l] * xn[(size_t)i1 * kE + l];
#pragma unroll
  for (int m = 32; m > 0; m >>= 1) v += __shfl_xor(v, m);
  if (l == 0) atomicAdd(&acc[k & 255], -10.f * v);
}

// ---------------- pairs: partial sumexp over a j-segment ----------------
__global__ __launch_bounds__(256) void lse_kernel(const float* __restrict__ xn,
                                                  const int* __restrict__ pairs,
                                                  float* __restrict__ pairsum) {
  constexpr int PPB = 16, TJ = 128, PAD = 4, JSEG = kN / 8;
  __shared__ float anch[PPB][kE];
  __shared__ float tileT[kE][TJ + PAD];
  const int t = threadIdx.x;
  const int pb = blockIdx.x * PPB;
  const int jbase = blockIdx.y * JSEG;
  for (int q = t; q < PPB * kE; q += 256) {
    int p = q >> 6, e = q & 63;
    anch[p][e] = xn[(size_t)pairs[2 * (pb + p)] * kE + e];
  }
  const int cg = t & 31;
  const int pg = t >> 5;
  const int c0 = cg * 4;
  const int p0 = 2 * pg, p1 = 2 * pg + 1;
  const int cload = t & 127;
  const int eb = t >> 7;
  float s0 = 0.f, s1 = 0.f;
  for (int j0 = jbase; j0 < jbase + JSEG; j0 += TJ) {
    __syncthreads();
#pragma unroll
    for (int i = 0; i < 8; ++i) {
      int e4 = (eb + 2 * i) * 4;
      float4 v = *(const float4*)(xn + (size_t)(j0 + cload) * kE + e4);
      tileT[e4 + 0][cload] = v.x;
      tileT[e4 + 1][cload] = v.y;
      tileT[e4 + 2][cload] = v.z;
      tileT[e4 + 3][cload] = v.w;
    }
    __syncthreads();
    float4 d0 = {0.f, 0.f, 0.f, 0.f}, d1 = {0.f, 0.f, 0.f, 0.f};
#pragma unroll
    for (int e = 0; e < kE; e += 4) {
      float4 a0 = *(const float4*)(&anch[p0][e]);
      float4 a1 = *(const float4*)(&anch[p1][e]);
      float4 t0 = *(const float4*)(&tileT[e + 0][c0]);
      float4 t1 = *(const float4*)(&tileT[e + 1][c0]);
      float4 t2 = *(const float4*)(&tileT[e + 2][c0]);
      float4 t3 = *(const float4*)(&tileT[e + 3][c0]);
#define ACC4(dd, aa, tt)              \
  dd.x = fmaf(aa, tt.x, dd.x);        \
  dd.y = fmaf(aa, tt.y, dd.y);        \
  dd.z = fmaf(aa, tt.z, dd.z);        \
  dd.w = fmaf(aa, tt.w, dd.w)
      ACC4(d0, a0.x, t0); ACC4(d0, a0.y, t1); ACC4(d0, a0.z, t2); ACC4(d0, a0.w, t3);
      ACC4(d1, a1.x, t0); ACC4(d1, a1.y, t1); ACC4(d1, a1.z, t2); ACC4(d1, a1.w, t3);
#undef ACC4
    }
    s0 += expf(10.f * d0.x) + expf(10.f * d0.y) + expf(10.f * d0.z) + expf(10.f * d0.w);
    s1 += expf(10.f * d1.x) + expf(10.f * d1.y) + expf(10.f * d1.z) + expf(10.f * d1.w);
  }
#pragma unroll
  for (int m = 16; m > 0; m >>= 1) {
    s0 += __shfl_xor(s0, m);
    s1 += __shfl_xor(s1, m);
  }
  if (cg == 0) {
    atomicAdd(&pairsum[pb + p0], s0);
    atomicAdd(&pairsum[pb + p1], s1);
  }
}

__global__ __launch_bounds__(256) void lse_log_kernel(const float* __restrict__ pairsum,
                                                      float* __restrict__ acc) {
  int p = blockIdx.x * 256 + threadIdx.x;
  atomicAdd(&acc[p & 255], logf(pairsum[p]));
}

// ---------------- finalize scalars ----------------
__global__ __launch_bounds__(256) void finalize_kernel(const float* __restrict__ acc,
                                                       float* __restrict__ out) {
  const int t = threadIdx.x;
  float vq = acc[t], qd = acc[256 + t], tr = acc[512 + t], ou = acc[768 + t];
#pragma unroll
  for (int m = 32; m > 0; m >>= 1) {
    vq += __shfl_xor(vq, m);
    qd += __shfl_xor(qd, m);
    tr += __shfl_xor(tr, m);
    ou += __shfl_xor(ou, m);
  }
  __shared__ float sm[4][4];
  const int w = t >> 6;
  if ((t & 63) == 0) { sm[0][w] = vq; sm[1][w] = qd; sm[2][w] = tr; sm[3][w] = ou; }
  __syncthreads();
  if (t == 0) {
    float svq = sm[0][0] + sm[0][1] + sm[0][2] + sm[0][3];
    float sqd = sm[1][0] + sm[1][1] + sm[1][2] + sm[1][3];
    float str = sm[2][0] + sm[2][1] + sm[2][2] + sm[2][3];
    float sou = sm[3][0] + sm[3][1] + sm[3][2] + sm[3][3];
    out[OFF_VQ]  = 1.001f * svq / (float)((size_t)kN * kE);
    out[OFF_OCL] = sou / (float)kKP;
    out[OFF_ITL] = str / (float)kTT;
    out[OFF_QDA] = 1.f - sqd / (float)kN;
  }
}

// ---------------- orchestration ----------------
extern "C" void kernel_launch(void* const* d_in, const int* in_sizes, int n_in,
                              void* d_out, int out_size, void* d_ws, size_t ws_size,
                              hipStream_t stream) {
  (void)in_sizes; (void)n_in; (void)out_size; (void)ws_size;
  const float* x    = (const float*)d_in[0];
  const float* qe   = (const float*)d_in[1];
  const float* qdw  = (const float*)d_in[2];
  const int*   prs  = (const int*)d_in[3];
  const int*   trs  = (const int*)d_in[4];
  const float* ew0  = (const float*)d_in[5];
  const float* eb0  = (const float*)d_in[6];
  const float* ew1  = (const float*)d_in[7];
  const float* eb1  = (const float*)d_in[8];
  const float* ew2  = (const float*)d_in[9];
  const float* eb2  = (const float*)d_in[10];
  const float* dw0  = (const float*)d_in[11];
  const float* db0  = (const float*)d_in[12];
  const float* dw1  = (const float*)d_in[13];
  const float* db1  = (const float*)d_in[14];
  const float* dw2  = (const float*)d_in[15];
  const float* db2  = (const float*)d_in[16];
  const float* cb   = (const float*)d_in[17];
  float* out = (float*)d_out;

  // ---- workspace carve-up (~114 MB) ----
  float* z   = (float*)d_ws;                         // N x E fp32
  float* qz  = z  + (size_t)kN * kE;
  float* xn  = qz + (size_t)kN * kE;
  float* acc = xn + (size_t)kN * kE;                 // 1024
  float* pairsum = acc + 1024;                       // 4096
  int*   flagcnt = (int*)(pairsum + 4096);           // 64 (1 used)
  int*   flags   = flagcnt + 64;                     // kN ints
  unsigned short* xqb  = (unsigned short*)(flags + kN);     // N x E bf16
  unsigned short* wt0h = xqb  + (size_t)kN * kE;     // enc w0^T hi 2048x768
  unsigned short* wt0l = wt0h + (size_t)kH1 * kIN;
  unsigned short* wt1h = wt0l + (size_t)kH1 * kIN;   // 1024x2048
  unsigned short* wt1l = wt1h + (size_t)kH2 * kH1;
  unsigned short* wt2h = wt1l + (size_t)kH2 * kH1;   // 64x1024
  unsigned short* wt2l = wt2h + (size_t)kE * kH2;
  unsigned short* wt3  = wt2l + (size_t)kE * kH2;    // dec w0^T 1024x64
  unsigned short* wt4  = wt3  + (size_t)kH2 * kE;    // dec w1^T 2048x1024
  unsigned short* wt5  = wt4  + (size_t)kH1 * kH2;   // dec w2^T 768x2048
  // chunk scratch (union across phases), 4096-row chunks
  unsigned short* xh  = wt5 + (size_t)kIN * kH1;     // 4096x768
  unsigned short* xl  = xh + (size_t)kCh * kIN;
  unsigned short* h1h = xl + (size_t)kCh * kIN;      // 4096x2048
  unsigned short* h1l = h1h + (size_t)kCh * kH1;
  unsigned short* h2h = h1l + (size_t)kCh * kH1;     // 4096x1024
  unsigned short* h2l = h2h + (size_t)kCh * kH2;

  hipMemsetAsync(acc, 0, (1024 + 4096 + 64) * sizeof(float), stream);

  // weight transposes: encoder split, decoder single
  transpose_bf16_split<<<dim3(kH1 / 32, kIN / 32), 256, 0, stream>>>(ew0, wt0h, wt0l, kIN, kH1);
  transpose_bf16_split<<<dim3(kH2 / 32, kH1 / 32), 256, 0, stream>>>(ew1, wt1h, wt1l, kH1, kH2);
  transpose_bf16_split<<<dim3(kE / 32, kH2 / 32), 256, 0, stream>>>(ew2, wt2h, wt2l, kH2, kE);
  transpose_bf16<<<dim3(kH2 / 32, kE / 32), 256, 0, stream>>>(dw0, wt3, kE, kH2);
  transpose_bf16<<<dim3(kH1 / 32, kH2 / 32), 256, 0, stream>>>(dw1, wt4, kH2, kH1);
  transpose_bf16<<<dim3(kIN / 32, kH1 / 32), 256, 0, stream>>>(dw2, wt5, kH1, kIN);

  // x-encoder (split-bf16 MFMA) -> z fp32
  for (int c = 0; c < kN / kCh; ++c) {
    conv_split<<<(kCh * kIN / 4 + 255) / 256, 256, 0, stream>>>(
        x + (size_t)c * kCh * kIN, xh, xl, kCh * kIN / 4);
    gemm_bt_split<128, 128, 64, true, 2>
        <<<dim3(kH1 / 128, kCh / 128), 256, 0, stream>>>(
            xh, xl, wt0h, wt0l, eb0, nullptr, h1h, h1l, kH1, kIN);
    gemm_bt_split<128, 128, 64, true, 2>
        <<<dim3(kH2 / 128, kCh / 128), 256, 0, stream>>>(
            h1h, h1l, wt1h, wt1l, eb1, nullptr, h2h, h2l, kH2, kH1);
    gemm_bt_split<128, 64, 64, false, 0>
        <<<dim3(kE / 64, kCh / 128), 256, 0, stream>>>(
            h2h, h2l, wt2h, wt2l, eb2, z + (size_t)c * kCh * kE, nullptr, nullptr,
            kE, kH2);
  }

  // VQ with gap-flagging, then exact fp32 fix for flagged rows
  vq_kernel<<<kN, 256, 0, stream>>>(z, cb, out + OFF_IDX, out + OFF_XQ, xqb, xn,
                                    acc, flags, flagcnt);
  fix_rows<<<64, 256, 0, stream>>>(x, ew0, eb0, ew1, eb1, ew2, eb2, cb, flags,
                                   flagcnt, z, out + OFF_IDX, out + OFF_XQ, xqb,
                                   xn, acc);

  // decoder (bf16 MFMA) on x_q_st -> out
  for (int c = 0; c < kN / kCh; ++c) {
    gemm_bt<128, 128, 64, true, false, true>
        <<<dim3(kH2 / 128, kCh / 128), 256, 0, stream>>>(
            xqb + (size_t)c * kCh * kE, wt3, db0, nullptr, h2h, kH2, kE);
    gemm_bt<128, 128, 64, true, false, true>
        <<<dim3(kH1 / 128, kCh / 128), 256, 0, stream>>>(
            h2h, wt4, db1, nullptr, h1h, kH1, kH2);
    gemm_bt<128, 128, 64, false, true, false>
        <<<dim3(kIN / 128, kCh / 128), 256, 0, stream>>>(
            h1h, wt5, db2, out + OFF_OUT + (size_t)c * kCh * kIN, nullptr, kIN, kH1);
  }

  // q-encoder (bf16 MFMA) -> qz
  for (int c = 0; c < kN / kCh; ++c) {
    conv_bf16<<<(kCh * kIN / 4 + 255) / 256, 256, 0, stream>>>(
        qe + (size_t)c * kCh * kIN, xh, kCh * kIN / 4);
    gemm_bt<128, 128, 64, true, false, true>
        <<<dim3(kH1 / 128, kCh / 128), 256, 0, stream>>>(
            xh, wt0h, eb0, nullptr, h1h, kH1, kIN);
    gemm_bt<128, 128, 64, true, false, true>
        <<<dim3(kH2 / 128, kCh / 128), 256, 0, stream>>>(
            h1h, wt1h, eb1, nullptr, h2h, kH2, kH1);
    gemm_bt<128, 64, 64, false, true, false>
        <<<dim3(kE / 64, kCh / 128), 256, 0, stream>>>(
            h2h, wt2h, eb2, qz + (size_t)c * kCh * kE, nullptr, kE, kH2);
  }

  // small loss kernels (all after fix_rows: z/xn final)
  qd_kernel<<<kN / 4, 256, 0, stream>>>(z, qz, qdw, acc + 256);
  trip_kernel<<<kTT / 4, 256, 0, stream>>>(z, trs, acc + 512);
  pos_kernel<<<kKP / 4, 256, 0, stream>>>(xn, prs, acc + 768);
  lse_kernel<<<dim3(kKP / 16, 8), 256, 0, stream>>>(xn, prs, pairsum);
  lse_log_kernel<<<kKP / 256, 256, 0, stream>>>(pairsum, acc + 768);

  finalize_kernel<<<1, 256, 0, stream>>>(acc, out);
}